// Round 18
// baseline (421.229 us; speedup 1.0000x reference)
//
#include <hip/hip_runtime.h>
#include <hip/hip_bf16.h>

#define NT 6
#define BM 256
#define BN 256
#define BK 64
#define SLOT_S 32768      // shorts per dbuf slot: A 32KB + B 32KB
// Fragment-major layout (shorts): A granule (mi,s,l) @ mi*2048 + s*512 + l*8
// (mi = 32-row subtile 0..7, s = K16 step 0..3, l = reader lane 0..63).
// B identical at +16384.
#define B_BASE 16384

typedef __attribute__((ext_vector_type(16))) float f32x16;
typedef __attribute__((ext_vector_type(8))) short bf16x8;

__device__ __forceinline__ short f2bf(float f) {
    __hip_bfloat16 h = __float2bfloat16(f);
    return (short)__builtin_bit_cast(unsigned short, h);
}

// ---- 1. segment argmax: packed (conf_bits<<32) | ~idx, atomicMax ----
__global__ void k_segmax(const float* __restrict__ conf,
                         const int* __restrict__ bidx,
                         unsigned long long* __restrict__ packed, int E) {
    int i = blockIdx.x * blockDim.x + threadIdx.x;
    if (i >= E) return;
    unsigned cb = __float_as_uint(conf[i]);
    unsigned long long p = ((unsigned long long)cb << 32) | (unsigned)(~(unsigned)i);
    atomicMax(&packed[bidx[i]], p);
}

// ---- 2. base[t][n] = emb[t] . W1[n,:d4] + b1[n]; extract conf/x/y columns ----
__global__ void k_base(const float* __restrict__ emb, const float* __restrict__ W1,
                       const float* __restrict__ b1, float* __restrict__ base,
                       float* __restrict__ vecs, int d2, int d4) {
    int gw = (blockIdx.x * blockDim.x + threadIdx.x) >> 6;
    int lane = threadIdx.x & 63;
    int t = gw / d2, n = gw % d2;
    const float* e = emb + (size_t)t * d4;
    const float* w = W1 + (size_t)n * (d4 + 3);
    float s = 0.f;
    for (int k = lane; k < d4; k += 64) s += e[k] * w[k];
#pragma unroll
    for (int m = 32; m; m >>= 1) s += __shfl_xor(s, m);
    if (lane == 0) {
        base[gw] = s + b1[n];
        if (t == 0) {
            vecs[n]          = w[d4];
            vecs[d2 + n]     = w[d4 + 1];
            vecs[2 * d2 + n] = w[d4 + 2];
        }
    }
}

// ---- 3. W2 fp32 -> bf16 ----
__global__ void k_w2cast(const float* __restrict__ W2, short* __restrict__ W2b, long n) {
    long i = ((long)blockIdx.x * blockDim.x + threadIdx.x) * 8;
    if (i >= n) return;
    bf16x8 v;
#pragma unroll
    for (int j = 0; j < 8; ++j) v[j] = f2bf(W2[i + j]);
    *(bf16x8*)(W2b + i) = v;
}

// ---- 4. h[b][n] = relu(base[t][n] + conf*cv[n] + lx*xv[n] + ly*yv[n]) -> bf16 ----
__global__ void k_h(const unsigned long long* __restrict__ packed,
                    const int* __restrict__ etype, const float* __restrict__ loc,
                    const float* __restrict__ base, const float* __restrict__ vecs,
                    float* __restrict__ mask, short* __restrict__ h, int d2) {
    int b = blockIdx.x;
    int tid = threadIdx.x;
    unsigned long long p = packed[b];
    bool has = (p != 0ULL);
    float conf = 0.f, lx = 0.f, ly = 0.f;
    int t = 0;
    if (has) {
        unsigned idx = ~(unsigned)(p & 0xFFFFFFFFu);
        conf = __uint_as_float((unsigned)(p >> 32));
        t  = etype[idx];
        lx = loc[2 * (size_t)idx]     * (1.0f / 640.0f);
        ly = loc[2 * (size_t)idx + 1] * (1.0f / 480.0f);
    }
    if (tid == 0) mask[b] = has ? 1.0f : 0.0f;
    const float* bs = base + (size_t)t * d2;
    const float* cv = vecs;
    const float* xv = vecs + d2;
    const float* yv = vecs + 2 * d2;
    int n0 = tid * 8;
    bf16x8 v;
#pragma unroll
    for (int j = 0; j < 8; ++j) {
        int n = n0 + j;
        float g = bs[n] + conf * cv[n] + lx * xv[n] + ly * yv[n];
        g = fmaxf(g, 0.f);
        v[j] = has ? f2bf(g) : (short)0;
    }
    *(bf16x8*)(h + (size_t)b * d2 + n0) = v;
}

// ---- 5. GEMM: R10 mega-phase + 32x32x16 MFMA + fragment-major LDS ----
// 256x256, BK=64, 2-slot dbuf (128 KiB), 8 waves (2x4), wave tile 128x64
// as 4m x 2n 32x32 tiles. Per K64 tile: {24 ds_read_b128; 8 GLL staging
// t+1; 32 MFMA_32x32x16 one cluster; vmcnt(0); barrier} — R10/R17's proven
// deep-queue schedule with the MFMA pipe cut 2484 -> 2066 cyc (m119).
// CONFLICT-FREE BY CONSTRUCTION: LDS is laid out fragment-major, so every
// fragment read is lane-linear (lane l reads base + l*16B, 1KB contiguous
// per wave) — no bank model needed (R16's conflicts came from a modeled
// pattern; this removes the model). The staging SOURCE carries the whole
// permutation (rule #21): thread tid of unit u sources
//   A[row0 + (2u+(tid>>8))*32 + (tid&31)][k-chunk 2*((tid>>6)&3)+((tid>>5)&1)]
// so that reader lane l of subtile (mi,s) receives
//   A[row0 + mi*32 + (l&31)][(2s + (l>>5))*8 ..] — the R5/R16-VERIFIED
// 32x32 operand layout. Epilogue mapping: R16-verified (passed absmax).

#define GLL(src, dst) __builtin_amdgcn_global_load_lds(                      \
    (const __attribute__((address_space(1))) void*)(src),                    \
    (__attribute__((address_space(3))) void*)(dst), 16, 0, 0)

// 4 GLL per operand: unit u covers rows 64u..64u+63 -> LDS +u*4096 shorts
#define ST_A(ws, kt) {                                                       \
    GLL(pA + (size_t)(kt) * 64,               (ws) + dstG);                  \
    GLL(pA + (size_t)64  * K + (kt) * 64,     (ws) + 4096  + dstG);          \
    GLL(pA + (size_t)128 * K + (kt) * 64,     (ws) + 8192  + dstG);          \
    GLL(pA + (size_t)192 * K + (kt) * 64,     (ws) + 12288 + dstG); }
#define ST_B(ws, kt) {                                                       \
    GLL(pB + (size_t)(kt) * 64,               (ws) + B_BASE + dstG);         \
    GLL(pB + (size_t)64  * K + (kt) * 64,     (ws) + B_BASE + 4096  + dstG); \
    GLL(pB + (size_t)128 * K + (kt) * 64,     (ws) + B_BASE + 8192  + dstG); \
    GLL(pB + (size_t)192 * K + (kt) * 64,     (ws) + B_BASE + 12288 + dstG); }

__global__ __launch_bounds__(512, 2)
void k_gemm(const short* __restrict__ A, const short* __restrict__ Bm,
            const float* __restrict__ b2, const float* __restrict__ mask,
            float* __restrict__ C, int M, int N, int K, int nbn) {
    __shared__ __align__(16) short lds[2 * SLOT_S];   // 128 KiB

    int tid = threadIdx.x;
    int lane = tid & 63;
    int wave = tid >> 6;            // 0..7
    int wr = wave >> 2, wc = wave & 3;

    // XCD-aware bijective swizzle (grid = 1024, % 8 == 0)
    int bid = blockIdx.x;
    int wg = (bid & 7) * ((int)gridDim.x >> 3) + (bid >> 3);
    int bm = wg / nbn, bn = wg % nbn;
    int row0 = bm * BM, col0 = bn * BN;

    // ---- staging precompute: inverse of the fragment-major layout ----
    int rA = ((tid >> 8) << 5) + (tid & 31);             // row within 64-row unit
    int cA = (((tid >> 6) & 3) << 1) + ((tid >> 5) & 1); // k-chunk 0..7
    const short* pA = A + (size_t)(row0 + rA) * K + cA * 8;
    const short* pB = Bm + (size_t)(col0 + rA) * K + cA * 8;
    int dstG = tid * 8;                                  // shorts (tid*16B)

    // ---- fragment read offsets: lane-linear (conflict-free) ----
    int l31 = lane & 31, kh = lane >> 5;
    int aBase = (wr * 4) * 2048 + lane * 8;              // + mi*2048 + s*512
    int bBase = B_BASE + (wc * 2) * 2048 + lane * 8;     // + ni*2048 + s*512

    f32x16 acc[4][2] = {};
    bf16x8 aA[4][4], bB[2][4];

    int KT = K / BK;                                     // 32

    // ---- prologue: stage tile 0 into slot 0, drain once ----
    ST_A(lds, 0); ST_B(lds, 0);
    asm volatile("s_waitcnt vmcnt(0)" ::: "memory");
    __builtin_amdgcn_s_barrier();

#pragma unroll 1
    for (int t = 0; t < KT; ++t) {
        const short* sl = lds + (t & 1) * SLOT_S;
        short* wsl = lds + ((t + 1) & 1) * SLOT_S;

        // ---- 24 ds_read_b128: whole tile's fragments (all lane-linear) ----
#pragma unroll
        for (int mi = 0; mi < 4; ++mi)
#pragma unroll
            for (int s = 0; s < 4; ++s)
                aA[mi][s] = *(const bf16x8*)(sl + aBase + mi * 2048 + s * 512);
#pragma unroll
        for (int ni = 0; ni < 2; ++ni)
#pragma unroll
            for (int s = 0; s < 4; ++s)
                bB[ni][s] = *(const bf16x8*)(sl + bBase + ni * 2048 + s * 512);

        // ---- stage tile t+1 (8 GLL) — lands under the MFMA cluster ----
        if (t < KT - 1) { ST_A(wsl, t + 1); ST_B(wsl, t + 1); }

        // ---- 32 MFMA 32x32x16, one cluster ----
#pragma unroll
        for (int mi = 0; mi < 4; ++mi)
#pragma unroll
            for (int ni = 0; ni < 2; ++ni)
#pragma unroll
                for (int s = 0; s < 4; ++s)
                    acc[mi][ni] = __builtin_amdgcn_mfma_f32_32x32x16_bf16(
                        aA[mi][s], bB[ni][s], acc[mi][ni], 0, 0, 0);

        if (t < KT - 1) {
            asm volatile("s_waitcnt vmcnt(0)" ::: "memory");
            __builtin_amdgcn_s_barrier();
        }
    }

    // ---- epilogue: +b2, *mask (R16-verified 32x32 C/D mapping) ----
#pragma unroll
    for (int mi = 0; mi < 4; ++mi) {
        int rb = row0 + wr * 128 + mi * 32 + 4 * kh;
#pragma unroll
        for (int q = 0; q < 4; ++q) {
#pragma unroll
            for (int j = 0; j < 4; ++j) {
                int r = rb + 8 * q + j;
                float mk = mask[r];
#pragma unroll
                for (int ni = 0; ni < 2; ++ni) {
                    int c = col0 + wc * 64 + ni * 32 + l31;
                    C[(size_t)r * N + c] = (acc[mi][ni][q * 4 + j] + b2[c]) * mk;
                }
            }
        }
    }
}

extern "C" void kernel_launch(void* const* d_in, const int* in_sizes, int n_in,
                              void* d_out, int out_size, void* d_ws, size_t ws_size,
                              hipStream_t stream) {
    const int* etype   = (const int*)d_in[0];
    const float* conf  = (const float*)d_in[1];
    const float* loc   = (const float*)d_in[2];
    const int* bidx    = (const int*)d_in[3];
    const float* emb   = (const float*)d_in[5];
    const float* W1    = (const float*)d_in[6];
    const float* b1    = (const float*)d_in[7];
    const float* W2    = (const float*)d_in[8];
    const float* b2    = (const float*)d_in[9];
    float* out = (float*)d_out;

    int E  = in_sizes[0];
    int d2 = in_sizes[7];           // 2048
    int d  = in_sizes[9];           // 4096
    int d4 = in_sizes[5] / NT;      // 1024
    int B  = out_size / d;          // 16384

    char* ws = (char*)d_ws;
    unsigned long long* packed = (unsigned long long*)ws;     // B*8
    float* mask = (float*)(ws + (size_t)B * 8);               // B*4
    float* base = mask + B;                                   // NT*d2
    float* vecs = base + NT * d2;                             // 3*d2
    short* w2b  = (short*)(vecs + 3 * d2);                    // d*d2 bf16
    short* h    = w2b + (size_t)d * d2;                       // B*d2 bf16

    hipMemsetAsync(packed, 0, (size_t)B * 8, stream);
    k_segmax<<<(E + 255) / 256, 256, 0, stream>>>(conf, bidx, packed, E);
    k_base<<<(NT * d2) / 4, 256, 0, stream>>>(emb, W1, b1, base, vecs, d2, d4);
    long nw2 = (long)d * d2;
    k_w2cast<<<(int)(nw2 / 8 / 256), 256, 0, stream>>>(W2, w2b, nw2);
    k_h<<<B, 256, 0, stream>>>(packed, etype, loc, base, vecs, mask, h, d2);
    int nbm = B / BM, nbn = d / BN;
    k_gemm<<<dim3(nbm * nbn), dim3(512), 0, stream>>>(h, w2b, b2, mask, out, B, d, d2, nbn);
}